// Round 2
// baseline (533.289 us; speedup 1.0000x reference)
//
#include <hip/hip_runtime.h>
#include <hip/hip_bf16.h>

// AudioCrossAttention on MI355X (gfx950).
// Pipeline: gemm<f32,bf16out> Q | gemm<f32,+lrope> K | gemm<f32,bf16out> V |
//           flash-attn (bf16 MFMA 16x16x32) | gemm<bf16,f32out> Out.
// All intermediates bf16 in d_ws (32 MB).

typedef short s16x8 __attribute__((ext_vector_type(8)));
typedef float f32x4 __attribute__((ext_vector_type(4)));

__device__ __forceinline__ short f2bf(float f) {
    unsigned u = __float_as_uint(f);
    u = u + 0x7fffu + ((u >> 16) & 1u);   // RNE
    return (short)(u >> 16);
}

// C[4096][1024] = X[4096][1024] @ W[1024][1024]^T + bias (+ optional LRoPE)
// XT: 0 = X f32, 1 = X bf16.  EPI: 0 = bf16 out, 1 = bf16 out + lrope(K), 2 = f32 out.
// 128x128 tile, BK=64, 4 waves, XOR-swizzled LDS (byte ^= (row&7)<<4).
template<int XT, int EPI>
__global__ __launch_bounds__(256)
void gemm_nt(const void* __restrict__ Xv, const float* __restrict__ W,
             const float* __restrict__ bias, void* __restrict__ Cv,
             const int* __restrict__ labels, const float* __restrict__ lemb)
{
    __shared__ __align__(16) short As[128 * 64];
    __shared__ __align__(16) short Bs[128 * 64];
    const int tid  = threadIdx.x;
    const int lane = tid & 63;
    const int wid  = tid >> 6;
    const int rowBase = blockIdx.y * 128;
    const int colBase = blockIdx.x * 128;
    const int wr = (wid >> 1) * 64;   // wave's 64-row strip
    const int wc = (wid & 1) * 64;    // wave's 64-col strip
    const float* Xf = (const float*)Xv;
    const short* Xb = (const short*)Xv;

    f32x4 acc[4][4] = {};

    for (int k0 = 0; k0 < 1024; k0 += 64) {
        __syncthreads();   // previous tile fully consumed
        #pragma unroll
        for (int i = 0; i < 4; ++i) {
            const int u   = i * 256 + tid;
            const int row = u >> 3;
            const int uf  = u & 7;
            const int byt = row * 128 + ((uf * 16) ^ ((row & 7) << 4));
            s16x8 pa;
            if (XT == 0) {
                const float* src = Xf + (size_t)(rowBase + row) * 1024 + k0 + uf * 8;
                float4 x0 = *(const float4*)src;
                float4 x1 = *(const float4*)(src + 4);
                pa[0]=f2bf(x0.x); pa[1]=f2bf(x0.y); pa[2]=f2bf(x0.z); pa[3]=f2bf(x0.w);
                pa[4]=f2bf(x1.x); pa[5]=f2bf(x1.y); pa[6]=f2bf(x1.z); pa[7]=f2bf(x1.w);
            } else {
                pa = *(const s16x8*)(Xb + (size_t)(rowBase + row) * 1024 + k0 + uf * 8);
            }
            *(s16x8*)((char*)As + byt) = pa;

            const float* srcB = W + (size_t)(colBase + row) * 1024 + k0 + uf * 8;
            float4 w0 = *(const float4*)srcB;
            float4 w1 = *(const float4*)(srcB + 4);
            s16x8 pb;
            pb[0]=f2bf(w0.x); pb[1]=f2bf(w0.y); pb[2]=f2bf(w0.z); pb[3]=f2bf(w0.w);
            pb[4]=f2bf(w1.x); pb[5]=f2bf(w1.y); pb[6]=f2bf(w1.z); pb[7]=f2bf(w1.w);
            *(s16x8*)((char*)Bs + byt) = pb;
        }
        __syncthreads();
        #pragma unroll
        for (int ks = 0; ks < 2; ++ks) {
            const int kb = ks * 64 + ((lane >> 4) << 4);  // byte offset of this lane's k-run
            s16x8 af[4], bfv[4];
            #pragma unroll
            for (int m = 0; m < 4; ++m) {
                const int row = wr + m * 16 + (lane & 15);
                af[m] = *(const s16x8*)((const char*)As + row * 128 + (kb ^ ((row & 7) << 4)));
            }
            #pragma unroll
            for (int n = 0; n < 4; ++n) {
                const int row = wc + n * 16 + (lane & 15);
                bfv[n] = *(const s16x8*)((const char*)Bs + row * 128 + (kb ^ ((row & 7) << 4)));
            }
            #pragma unroll
            for (int m = 0; m < 4; ++m)
                #pragma unroll
                for (int n = 0; n < 4; ++n)
                    acc[m][n] = __builtin_amdgcn_mfma_f32_16x16x32_bf16(af[m], bfv[n], acc[m][n], 0, 0, 0);
        }
    }

    short* Cb = (short*)Cv;
    float* Cf = (float*)Cv;
    #pragma unroll
    for (int m = 0; m < 4; ++m) {
        #pragma unroll
        for (int r = 0; r < 4; ++r) {
            const int grow = rowBase + wr + m * 16 + ((lane >> 4) << 2) + r;
            #pragma unroll
            for (int n = 0; n < 4; ++n) {
                const int gcol = colBase + wc + n * 16 + (lane & 15);
                float v = acc[m][n][r] + bias[gcol];
                if (EPI == 1) {
                    const int bb = grow >> 11;          // batch
                    const int ss = grow & 2047;         // kv position
                    const int hd = gcol & 63;           // within head
                    const int fi = hd & 31;
                    const float ang = (float)ss * __expf((float)fi * (-9.210340371976184f / 32.0f));
                    const float tr  = (hd < 32) ? sinf(ang) : cosf(ang);
                    v += tr * lemb[labels[bb] * 64 + hd];
                }
                if (EPI == 2) Cf[(size_t)grow * 1024 + gcol] = v;
                else          Cb[(size_t)grow * 1024 + gcol] = f2bf(v);
            }
        }
    }
}

// Flash attention: grid (32 q-tiles, 32 b*h), 256 thr = 4 waves x 16 q-rows.
// KV tiles of 64. K staged row-major swizzled; V staged TRANSPOSED (Vt[d][kv]) swizzled.
// Online softmax wave-parallel via shfl_xor over the 16-lane column groups.
__global__ __launch_bounds__(256)
void attn_fwd(const short* __restrict__ Q, const short* __restrict__ Kt,
              const short* __restrict__ V, short* __restrict__ AO)
{
    __shared__ __align__(16) short Ks[64 * 64];
    __shared__ __align__(16) short Vt[64 * 64];
    __shared__ __align__(16) short Ps[4][16 * 64];
    const int tid  = threadIdx.x;
    const int lane = tid & 63;
    const int wid  = tid >> 6;
    const int qt = blockIdx.x;
    const int bh = blockIdx.y;
    const int b  = bh >> 4, h = bh & 15;
    const int qrow0 = b * 2048 + qt * 64;
    const int krow0 = b * 2048;
    const int hoff  = h * 64;

    // Q fragments hoisted to registers (wave's 16 rows, full d=64)
    s16x8 qf[2];
    {
        const int qr = qrow0 + wid * 16 + (lane & 15);
        const short* qp = Q + (size_t)qr * 1024 + hoff + ((lane >> 4) << 3);
        qf[0] = *(const s16x8*)(qp);
        qf[1] = *(const s16x8*)(qp + 32);
    }

    float mrun[4], lrun[4];
    f32x4 o[4] = {};
    #pragma unroll
    for (int r = 0; r < 4; ++r) { mrun[r] = -1e30f; lrun[r] = 0.f; }

    for (int kv0 = 0; kv0 < 2048; kv0 += 64) {
        __syncthreads();   // all waves done reading previous K/V tile
        #pragma unroll
        for (int i = 0; i < 2; ++i) {
            const int u  = i * 256 + tid;
            const int kr = u >> 3;        // kv row within tile
            const int uf = u & 7;         // 8-element chunk along d
            const size_t goff = (size_t)(krow0 + kv0 + kr) * 1024 + hoff + uf * 8;
            s16x8 kvv = *(const s16x8*)(Kt + goff);
            *(s16x8*)((char*)Ks + kr * 128 + ((uf * 16) ^ ((kr & 7) << 4))) = kvv;
            s16x8 vv = *(const s16x8*)(V + goff);
            #pragma unroll
            for (int jj = 0; jj < 8; ++jj) {
                const int j = (jj + uf) & 7;      // lane-rotated to spread banks
                const int d = uf * 8 + j;
                *(short*)((char*)Vt + d * 128 + ((kr * 2) ^ ((d & 7) << 4))) = vv[j];
            }
        }
        __syncthreads();

        // S = Q K^T  (4 col-fragments of 16 kv each)
        f32x4 s[4] = {};
        #pragma unroll
        for (int ks = 0; ks < 2; ++ks) {
            const int kb = ks * 64 + ((lane >> 4) << 4);
            #pragma unroll
            for (int n = 0; n < 4; ++n) {
                const int row = n * 16 + (lane & 15);
                s16x8 kf = *(const s16x8*)((const char*)Ks + row * 128 + (kb ^ ((row & 7) << 4)));
                s[n] = __builtin_amdgcn_mfma_f32_16x16x32_bf16(qf[ks], kf, s[n], 0, 0, 0);
            }
        }
        #pragma unroll
        for (int n = 0; n < 4; ++n) s[n] *= 0.125f;   // scale = hd^-0.5

        // online softmax (row r lives on 16 lanes sharing lane>>4)
        float al[4];
        #pragma unroll
        for (int r = 0; r < 4; ++r) {
            float pm = fmaxf(fmaxf(s[0][r], s[1][r]), fmaxf(s[2][r], s[3][r]));
            pm = fmaxf(pm, __shfl_xor(pm, 1));
            pm = fmaxf(pm, __shfl_xor(pm, 2));
            pm = fmaxf(pm, __shfl_xor(pm, 4));
            pm = fmaxf(pm, __shfl_xor(pm, 8));
            const float mn = fmaxf(mrun[r], pm);
            al[r] = __expf(mrun[r] - mn);
            mrun[r] = mn;
            float rs = 0.f;
            #pragma unroll
            for (int n = 0; n < 4; ++n) {
                const float p = __expf(s[n][r] - mn);
                s[n][r] = p;
                rs += p;
            }
            rs += __shfl_xor(rs, 1);
            rs += __shfl_xor(rs, 2);
            rs += __shfl_xor(rs, 4);
            rs += __shfl_xor(rs, 8);
            lrun[r] = lrun[r] * al[r] + rs;
        }

        // write P strip (per-wave, swizzled) + rescale O
        #pragma unroll
        for (int n = 0; n < 4; ++n) {
            #pragma unroll
            for (int r = 0; r < 4; ++r) {
                const int row = ((lane >> 4) << 2) + r;
                const int col = n * 16 + (lane & 15);
                *(short*)((char*)&Ps[wid][0] + row * 128 + ((col * 2) ^ ((row & 7) << 4))) = f2bf(s[n][r]);
                o[n][r] *= al[r];
            }
        }
        asm volatile("s_waitcnt lgkmcnt(0)" ::: "memory");  // wave-local P write -> read

        // O += P @ V
        #pragma unroll
        for (int ks = 0; ks < 2; ++ks) {
            const int kb = ks * 64 + ((lane >> 4) << 4);
            const int prow = lane & 15;
            s16x8 pa = *(const s16x8*)((const char*)&Ps[wid][0] + prow * 128 + (kb ^ ((prow & 7) << 4)));
            #pragma unroll
            for (int n = 0; n < 4; ++n) {
                const int row = n * 16 + (lane & 15);
                s16x8 vb = *(const s16x8*)((const char*)Vt + row * 128 + (kb ^ ((row & 7) << 4)));
                o[n] = __builtin_amdgcn_mfma_f32_16x16x32_bf16(pa, vb, o[n], 0, 0, 0);
            }
        }
    }

    #pragma unroll
    for (int r = 0; r < 4; ++r) {
        const float inv = 1.0f / lrun[r];
        const int grow = qrow0 + wid * 16 + ((lane >> 4) << 2) + r;
        #pragma unroll
        for (int n = 0; n < 4; ++n) {
            const int gcol = hoff + n * 16 + (lane & 15);
            AO[(size_t)grow * 1024 + gcol] = f2bf(o[n][r] * inv);
        }
    }
}

extern "C" void kernel_launch(void* const* d_in, const int* in_sizes, int n_in,
                              void* d_out, int out_size, void* d_ws, size_t ws_size,
                              hipStream_t stream) {
    const float* vis    = (const float*)d_in[0];
    const float* aud    = (const float*)d_in[1];
    const int*   labels = (const int*)d_in[2];
    const float* Wq = (const float*)d_in[3];  const float* bq = (const float*)d_in[4];
    const float* Wk = (const float*)d_in[5];  const float* bk = (const float*)d_in[6];
    const float* Wv = (const float*)d_in[7];  const float* bv = (const float*)d_in[8];
    const float* Wo = (const float*)d_in[9];  const float* bo = (const float*)d_in[10];
    const float* lemb = (const float*)d_in[11];

    short* wsQ  = (short*)d_ws;               // 4096*1024 bf16 = 8 MB each
    short* wsK  = wsQ  + 4096 * 1024;
    short* wsV  = wsK  + 4096 * 1024;
    short* wsAO = wsV  + 4096 * 1024;
    float* out  = (float*)d_out;

    dim3 gg(8, 32);
    gemm_nt<0, 0><<<gg, 256, 0, stream>>>(vis, Wq, bq, wsQ,  nullptr, nullptr);
    gemm_nt<0, 1><<<gg, 256, 0, stream>>>(aud, Wk, bk, wsK,  labels, lemb);
    gemm_nt<0, 0><<<gg, 256, 0, stream>>>(aud, Wv, bv, wsV,  nullptr, nullptr);
    attn_fwd<<<dim3(32, 32), 256, 0, stream>>>(wsQ, wsK, wsV, wsAO);
    gemm_nt<1, 2><<<gg, 256, 0, stream>>>(wsAO, Wo, bo, out, nullptr, nullptr);
}

// Round 3
// 431.212 us; speedup vs baseline: 1.2367x; 1.2367x over previous
//
#include <hip/hip_runtime.h>
#include <hip/hip_bf16.h>

// AudioCrossAttention on MI355X (gfx950).
// Pipeline: cvt(all f32->bf16) | gemm_bf16 Q | gemm_bf16+lrope K | gemm_bf16 V |
//           flash-attn | gemm_bf16 -> f32 out.
// GEMM: 128x128 tile, BK=64, global_load_lds dwordx4 staging, double-buffered LDS,
//       2-phase pipeline (prefetch t+1 before compute t), swizzled reads via
//       inverse-swizzled global source (rule #21c: linear dest + swz source + swz read).

typedef short s16x8 __attribute__((ext_vector_type(8)));
typedef float f32x4 __attribute__((ext_vector_type(4)));

__device__ __forceinline__ short f2bf(float f) {
    unsigned u = __float_as_uint(f);
    u = u + 0x7fffu + ((u >> 16) & 1u);   // RNE
    return (short)(u >> 16);
}

#define GLDS16(g, l)                                                          \
    __builtin_amdgcn_global_load_lds(                                         \
        (const __attribute__((address_space(1))) void*)(g),                   \
        (__attribute__((address_space(3))) void*)(l), 16, 0, 0)

// ---------------------------------------------------------------------------
// Convert all f32 operands to bf16 (one s16x8 per thread per block-slot).
// Blocks: [0,2048) vis, [2048,4096) aud, then 512 each for Wq,Wk,Wv,Wo.
__global__ __launch_bounds__(256)
void cvt_all(const float* __restrict__ vis, const float* __restrict__ aud,
             const float* __restrict__ Wq, const float* __restrict__ Wk,
             const float* __restrict__ Wv, const float* __restrict__ Wo,
             short* __restrict__ visB, short* __restrict__ audB,
             short* __restrict__ WqB, short* __restrict__ WkB,
             short* __restrict__ WvB, short* __restrict__ WoB)
{
    const int bid = blockIdx.x;
    const float* src; short* dst; int vec0;
    if (bid < 2048)      { src = vis; dst = visB; vec0 = bid * 256; }
    else if (bid < 4096) { src = aud; dst = audB; vec0 = (bid - 4096 + 2048) * 256; }
    else {
        const int r = bid - 4096, w = r >> 9, lb = r & 511;
        vec0 = lb * 256;
        if      (w == 0) { src = Wq; dst = WqB; }
        else if (w == 1) { src = Wk; dst = WkB; }
        else if (w == 2) { src = Wv; dst = WvB; }
        else             { src = Wo; dst = WoB; }
    }
    const int i = (vec0 + threadIdx.x) * 8;
    float4 a = *(const float4*)(src + i);
    float4 b = *(const float4*)(src + i + 4);
    s16x8 o;
    o[0]=f2bf(a.x); o[1]=f2bf(a.y); o[2]=f2bf(a.z); o[3]=f2bf(a.w);
    o[4]=f2bf(b.x); o[5]=f2bf(b.y); o[6]=f2bf(b.z); o[7]=f2bf(b.w);
    *(s16x8*)(dst + i) = o;
}

// ---------------------------------------------------------------------------
// C[4096][1024] = X[4096][1024] @ W[1024][1024]^T + bias (+ optional LRoPE).
// X, W bf16; EPI: 0 = bf16 out, 1 = bf16 out + lrope(K), 2 = f32 out.
template<int EPI>
__global__ __launch_bounds__(256)
void gemm_bf16(const short* __restrict__ X, const short* __restrict__ W,
               const float* __restrict__ bias, void* __restrict__ Cv,
               const int* __restrict__ labels, const float* __restrict__ lemb)
{
    __shared__ __align__(16) short As[2][128 * 64];
    __shared__ __align__(16) short Bs[2][128 * 64];
    const int tid  = threadIdx.x;
    const int lane = tid & 63;
    const int wid  = tid >> 6;
    const int rowBase = blockIdx.y * 128;
    const int colBase = blockIdx.x * 128;
    const int wr = (wid >> 1) * 64;
    const int wc = (wid & 1) * 64;

    f32x4 acc[4][4] = {};

    // Staging: wave-call c covers LDS bytes (wid*4+c)*1024..+1023 (linear, lane*16).
    // Lane's global chunk is inverse-swizzled: k8' = (u&7) ^ (row&7), row = u>>3,
    // so that the swizzled ds_read (byte ^= (row&7)<<4) recovers linear k-runs.
    auto stage = [&](int buf, int k0) {
        #pragma unroll
        for (int c = 0; c < 4; ++c) {
            const int u   = (wid * 4 + c) * 64 + lane;
            const int row = u >> 3;
            const int k8a = (u & 7) ^ (row & 7);
            GLDS16(X + (size_t)(rowBase + row) * 1024 + k0 + k8a * 8,
                   &As[buf][(wid * 4 + c) * 512]);
            GLDS16(W + (size_t)(colBase + row) * 1024 + k0 + k8a * 8,
                   &Bs[buf][(wid * 4 + c) * 512]);
        }
    };

    stage(0, 0);
    __syncthreads();   // drains vmcnt: tile 0 resident

    for (int t = 0; t < 16; ++t) {
        const int cur = t & 1;
        if (t < 15) stage(cur ^ 1, (t + 1) * 64);   // prefetch under compute
        #pragma unroll
        for (int ks = 0; ks < 2; ++ks) {
            const int kb = ks * 64 + ((lane >> 4) << 4);
            s16x8 af[4], bfv[4];
            #pragma unroll
            for (int m = 0; m < 4; ++m) {
                const int row = wr + m * 16 + (lane & 15);
                af[m] = *(const s16x8*)((const char*)&As[cur][0] + row * 128 + (kb ^ ((row & 7) << 4)));
            }
            #pragma unroll
            for (int n = 0; n < 4; ++n) {
                const int row = wc + n * 16 + (lane & 15);
                bfv[n] = *(const s16x8*)((const char*)&Bs[cur][0] + row * 128 + (kb ^ ((row & 7) << 4)));
            }
            #pragma unroll
            for (int m = 0; m < 4; ++m)
                #pragma unroll
                for (int n = 0; n < 4; ++n)
                    acc[m][n] = __builtin_amdgcn_mfma_f32_16x16x32_bf16(af[m], bfv[n], acc[m][n], 0, 0, 0);
        }
        __syncthreads();   // drains vmcnt (prefetch landed) + all reads of cur done
    }

    short* Cb = (short*)Cv;
    float* Cf = (float*)Cv;
    #pragma unroll
    for (int m = 0; m < 4; ++m) {
        #pragma unroll
        for (int r = 0; r < 4; ++r) {
            const int grow = rowBase + wr + m * 16 + ((lane >> 4) << 2) + r;
            #pragma unroll
            for (int n = 0; n < 4; ++n) {
                const int gcol = colBase + wc + n * 16 + (lane & 15);
                float v = acc[m][n][r] + bias[gcol];
                if (EPI == 1) {
                    const int bb = grow >> 11;          // batch
                    const int ss = grow & 2047;         // kv position
                    const int hd = gcol & 63;           // within head
                    const int fi = hd & 31;
                    const float ang = (float)ss * __expf((float)fi * (-9.210340371976184f / 32.0f));
                    const float tr  = (hd < 32) ? sinf(ang) : cosf(ang);
                    v += tr * lemb[labels[bb] * 64 + hd];
                }
                if (EPI == 2) Cf[(size_t)grow * 1024 + gcol] = v;
                else          Cb[(size_t)grow * 1024 + gcol] = f2bf(v);
            }
        }
    }
}

// ---------------------------------------------------------------------------
// Flash attention: grid (32 q-tiles, 32 b*h), 256 thr = 4 waves x 16 q-rows.
// (unchanged from round 2 — counters next round will show its true share)
__global__ __launch_bounds__(256)
void attn_fwd(const short* __restrict__ Q, const short* __restrict__ Kt,
              const short* __restrict__ V, short* __restrict__ AO)
{
    __shared__ __align__(16) short Ks[64 * 64];
    __shared__ __align__(16) short Vt[64 * 64];
    __shared__ __align__(16) short Ps[4][16 * 64];
    const int tid  = threadIdx.x;
    const int lane = tid & 63;
    const int wid  = tid >> 6;
    const int qt = blockIdx.x;
    const int bh = blockIdx.y;
    const int b  = bh >> 4, h = bh & 15;
    const int qrow0 = b * 2048 + qt * 64;
    const int krow0 = b * 2048;
    const int hoff  = h * 64;

    s16x8 qf[2];
    {
        const int qr = qrow0 + wid * 16 + (lane & 15);
        const short* qp = Q + (size_t)qr * 1024 + hoff + ((lane >> 4) << 3);
        qf[0] = *(const s16x8*)(qp);
        qf[1] = *(const s16x8*)(qp + 32);
    }

    float mrun[4], lrun[4];
    f32x4 o[4] = {};
    #pragma unroll
    for (int r = 0; r < 4; ++r) { mrun[r] = -1e30f; lrun[r] = 0.f; }

    for (int kv0 = 0; kv0 < 2048; kv0 += 64) {
        __syncthreads();
        #pragma unroll
        for (int i = 0; i < 2; ++i) {
            const int u  = i * 256 + tid;
            const int kr = u >> 3;
            const int uf = u & 7;
            const size_t goff = (size_t)(krow0 + kv0 + kr) * 1024 + hoff + uf * 8;
            s16x8 kvv = *(const s16x8*)(Kt + goff);
            *(s16x8*)((char*)Ks + kr * 128 + ((uf * 16) ^ ((kr & 7) << 4))) = kvv;
            s16x8 vv = *(const s16x8*)(V + goff);
            #pragma unroll
            for (int jj = 0; jj < 8; ++jj) {
                const int j = (jj + uf) & 7;
                const int d = uf * 8 + j;
                *(short*)((char*)Vt + d * 128 + ((kr * 2) ^ ((d & 7) << 4))) = vv[j];
            }
        }
        __syncthreads();

        f32x4 s[4] = {};
        #pragma unroll
        for (int ks = 0; ks < 2; ++ks) {
            const int kb = ks * 64 + ((lane >> 4) << 4);
            #pragma unroll
            for (int n = 0; n < 4; ++n) {
                const int row = n * 16 + (lane & 15);
                s16x8 kf = *(const s16x8*)((const char*)Ks + row * 128 + (kb ^ ((row & 7) << 4)));
                s[n] = __builtin_amdgcn_mfma_f32_16x16x32_bf16(qf[ks], kf, s[n], 0, 0, 0);
            }
        }
        #pragma unroll
        for (int n = 0; n < 4; ++n) s[n] *= 0.125f;

        float al[4];
        #pragma unroll
        for (int r = 0; r < 4; ++r) {
            float pm = fmaxf(fmaxf(s[0][r], s[1][r]), fmaxf(s[2][r], s[3][r]));
            pm = fmaxf(pm, __shfl_xor(pm, 1));
            pm = fmaxf(pm, __shfl_xor(pm, 2));
            pm = fmaxf(pm, __shfl_xor(pm, 4));
            pm = fmaxf(pm, __shfl_xor(pm, 8));
            const float mn = fmaxf(mrun[r], pm);
            al[r] = __expf(mrun[r] - mn);
            mrun[r] = mn;
            float rs = 0.f;
            #pragma unroll
            for (int n = 0; n < 4; ++n) {
                const float p = __expf(s[n][r] - mn);
                s[n][r] = p;
                rs += p;
            }
            rs += __shfl_xor(rs, 1);
            rs += __shfl_xor(rs, 2);
            rs += __shfl_xor(rs, 4);
            rs += __shfl_xor(rs, 8);
            lrun[r] = lrun[r] * al[r] + rs;
        }

        #pragma unroll
        for (int n = 0; n < 4; ++n) {
            #pragma unroll
            for (int r = 0; r < 4; ++r) {
                const int row = ((lane >> 4) << 2) + r;
                const int col = n * 16 + (lane & 15);
                *(short*)((char*)&Ps[wid][0] + row * 128 + ((col * 2) ^ ((row & 7) << 4))) = f2bf(s[n][r]);
                o[n][r] *= al[r];
            }
        }
        asm volatile("s_waitcnt lgkmcnt(0)" ::: "memory");

        #pragma unroll
        for (int ks = 0; ks < 2; ++ks) {
            const int kb = ks * 64 + ((lane >> 4) << 4);
            const int prow = lane & 15;
            s16x8 pa = *(const s16x8*)((const char*)&Ps[wid][0] + prow * 128 + (kb ^ ((prow & 7) << 4)));
            #pragma unroll
            for (int n = 0; n < 4; ++n) {
                const int row = n * 16 + (lane & 15);
                s16x8 vb = *(const s16x8*)((const char*)Vt + row * 128 + (kb ^ ((row & 7) << 4)));
                o[n] = __builtin_amdgcn_mfma_f32_16x16x32_bf16(pa, vb, o[n], 0, 0, 0);
            }
        }
    }

    #pragma unroll
    for (int r = 0; r < 4; ++r) {
        const float inv = 1.0f / lrun[r];
        const int grow = qrow0 + wid * 16 + ((lane >> 4) << 2) + r;
        #pragma unroll
        for (int n = 0; n < 4; ++n) {
            const int gcol = hoff + n * 16 + (lane & 15);
            AO[(size_t)grow * 1024 + gcol] = f2bf(o[n][r] * inv);
        }
    }
}

extern "C" void kernel_launch(void* const* d_in, const int* in_sizes, int n_in,
                              void* d_out, int out_size, void* d_ws, size_t ws_size,
                              hipStream_t stream) {
    const float* vis    = (const float*)d_in[0];
    const float* aud    = (const float*)d_in[1];
    const int*   labels = (const int*)d_in[2];
    const float* Wq = (const float*)d_in[3];  const float* bq = (const float*)d_in[4];
    const float* Wk = (const float*)d_in[5];  const float* bk = (const float*)d_in[6];
    const float* Wv = (const float*)d_in[7];  const float* bv = (const float*)d_in[8];
    const float* Wo = (const float*)d_in[9];  const float* bo = (const float*)d_in[10];
    const float* lemb = (const float*)d_in[11];

    // ws layout (shorts): Q,K,V,AO 4M each; then visB,audB 4M each; WqB..WoB 1M each.
    short* wsQ   = (short*)d_ws;
    short* wsK   = wsQ  + 4194304;
    short* wsV   = wsK  + 4194304;
    short* wsAO  = wsV  + 4194304;
    short* visB  = wsAO + 4194304;
    short* audB  = visB + 4194304;
    short* WqB   = audB + 4194304;
    short* WkB   = WqB  + 1048576;
    short* WvB   = WkB  + 1048576;
    short* WoB   = WvB  + 1048576;
    float* out   = (float*)d_out;

    cvt_all<<<6144, 256, 0, stream>>>(vis, aud, Wq, Wk, Wv, Wo,
                                      visB, audB, WqB, WkB, WvB, WoB);
    dim3 gg(8, 32);
    gemm_bf16<0><<<gg, 256, 0, stream>>>(visB, WqB, bq, wsQ,  nullptr, nullptr);
    gemm_bf16<1><<<gg, 256, 0, stream>>>(audB, WkB, bk, wsK,  labels, lemb);
    gemm_bf16<0><<<gg, 256, 0, stream>>>(audB, WvB, bv, wsV,  nullptr, nullptr);
    attn_fwd<<<dim3(32, 32), 256, 0, stream>>>(wsQ, wsK, wsV, wsAO);
    gemm_bf16<2><<<gg, 256, 0, stream>>>(wsAO, WoB, bo, out, nullptr, nullptr);
}

// Round 4
// 261.704 us; speedup vs baseline: 2.0378x; 1.6477x over previous
//
#include <hip/hip_runtime.h>
#include <hip/hip_bf16.h>

// AudioCrossAttention on MI355X (gfx950).
// cvt(f32->bf16) | gemm_qkv (fused Q/K/V; K+lrope; V writes V^T) |
// flash-attn (GLDS-staged K/V^T, defer-max softmax) | gemm_bf16<2> -> f32 out.

typedef short s16x8 __attribute__((ext_vector_type(8)));
typedef float f32x4 __attribute__((ext_vector_type(4)));

__device__ __forceinline__ short f2bf(float f) {
    unsigned u = __float_as_uint(f);
    u = u + 0x7fffu + ((u >> 16) & 1u);   // RNE
    return (short)(u >> 16);
}

#define GLDS16(g, l)                                                          \
    __builtin_amdgcn_global_load_lds(                                         \
        (const __attribute__((address_space(1))) void*)(g),                   \
        (__attribute__((address_space(3))) void*)(l), 16, 0, 0)

// ---------------------------------------------------------------------------
__global__ __launch_bounds__(256)
void cvt_all(const float* __restrict__ vis, const float* __restrict__ aud,
             const float* __restrict__ Wq, const float* __restrict__ Wk,
             const float* __restrict__ Wv, const float* __restrict__ Wo,
             short* __restrict__ visB, short* __restrict__ audB,
             short* __restrict__ WqB, short* __restrict__ WkB,
             short* __restrict__ WvB, short* __restrict__ WoB)
{
    const int bid = blockIdx.x;
    const float* src; short* dst; int vec0;
    if (bid < 2048)      { src = vis; dst = visB; vec0 = bid * 256; }
    else if (bid < 4096) { src = aud; dst = audB; vec0 = (bid - 2048) * 256; }
    else {
        const int r = bid - 4096, w = r >> 9, lb = r & 511;
        vec0 = lb * 256;
        if      (w == 0) { src = Wq; dst = WqB; }
        else if (w == 1) { src = Wk; dst = WkB; }
        else if (w == 2) { src = Wv; dst = WvB; }
        else             { src = Wo; dst = WoB; }
    }
    const int i = (vec0 + threadIdx.x) * 8;
    float4 a = *(const float4*)(src + i);
    float4 b = *(const float4*)(src + i + 4);
    s16x8 o;
    o[0]=f2bf(a.x); o[1]=f2bf(a.y); o[2]=f2bf(a.z); o[3]=f2bf(a.w);
    o[4]=f2bf(b.x); o[5]=f2bf(b.y); o[6]=f2bf(b.z); o[7]=f2bf(b.w);
    *(s16x8*)(dst + i) = o;
}

// ---------------------------------------------------------------------------
// Fused Q/K/V projection. blockIdx.z: 0=Q (prescaled 0.125), 1=K (+lrope),
// 2=V (writes V^T per-head [bh][64 d][2048 kv]).
__global__ __launch_bounds__(256)
void gemm_qkv(const short* __restrict__ visB, const short* __restrict__ audB,
              const short* __restrict__ WqB, const short* __restrict__ WkB,
              const short* __restrict__ WvB,
              const float* __restrict__ bq, const float* __restrict__ bk,
              const float* __restrict__ bv,
              short* __restrict__ outQ, short* __restrict__ outK,
              short* __restrict__ outVt,
              const int* __restrict__ labels, const float* __restrict__ lemb)
{
    __shared__ __align__(16) short As[2][128 * 64];
    __shared__ __align__(16) short Bs[2][128 * 64];
    const int tid  = threadIdx.x;
    const int lane = tid & 63;
    const int wid  = tid >> 6;
    const int z    = blockIdx.z;
    const int rowBase = blockIdx.y * 128;
    const int colBase = blockIdx.x * 128;
    const int wr = (wid >> 1) * 64;
    const int wc = (wid & 1) * 64;
    const short* X = (z == 0) ? visB : audB;
    const short* W = (z == 0) ? WqB : (z == 1) ? WkB : WvB;
    const float* bias = (z == 0) ? bq : (z == 1) ? bk : bv;

    f32x4 acc[4][4] = {};

    auto stage = [&](int buf, int k0) {
        #pragma unroll
        for (int c = 0; c < 4; ++c) {
            const int u   = (wid * 4 + c) * 64 + lane;
            const int row = u >> 3;
            const int k8a = (u & 7) ^ (row & 7);
            GLDS16(X + (size_t)(rowBase + row) * 1024 + k0 + k8a * 8,
                   &As[buf][(wid * 4 + c) * 512]);
            GLDS16(W + (size_t)(colBase + row) * 1024 + k0 + k8a * 8,
                   &Bs[buf][(wid * 4 + c) * 512]);
        }
    };

    stage(0, 0);
    __syncthreads();

    for (int t = 0; t < 16; ++t) {
        const int cur = t & 1;
        if (t < 15) stage(cur ^ 1, (t + 1) * 64);
        #pragma unroll
        for (int ks = 0; ks < 2; ++ks) {
            const int kb = ks * 64 + ((lane >> 4) << 4);
            s16x8 af[4], bfv[4];
            #pragma unroll
            for (int m = 0; m < 4; ++m) {
                const int row = wr + m * 16 + (lane & 15);
                af[m] = *(const s16x8*)((const char*)&As[cur][0] + row * 128 + (kb ^ ((row & 7) << 4)));
            }
            #pragma unroll
            for (int n = 0; n < 4; ++n) {
                const int row = wc + n * 16 + (lane & 15);
                bfv[n] = *(const s16x8*)((const char*)&Bs[cur][0] + row * 128 + (kb ^ ((row & 7) << 4)));
            }
            #pragma unroll
            for (int m = 0; m < 4; ++m)
                #pragma unroll
                for (int n = 0; n < 4; ++n)
                    acc[m][n] = __builtin_amdgcn_mfma_f32_16x16x32_bf16(af[m], bfv[n], acc[m][n], 0, 0, 0);
        }
        __syncthreads();
    }

    if (z == 2) {
        // Per-wave transpose through LDS (reuse As): wave tile = 64 kv x 64 d
        // (one head). Write swizzled [hd][kv], read rows, store V^T coalesced.
        char* tb = (char*)&As[0][0] + wid * 8192;
        const int b  = rowBase >> 11;
        const int h  = (colBase + wc) >> 6;
        const int kvbase = (rowBase & 2047) + wr;
        #pragma unroll
        for (int m = 0; m < 4; ++m) {
            #pragma unroll
            for (int r = 0; r < 4; ++r) {
                const int kvl = m * 16 + ((lane >> 4) << 2) + r;
                #pragma unroll
                for (int n = 0; n < 4; ++n) {
                    const int hd = n * 16 + (lane & 15);
                    const float v = acc[m][n][r] + bias[colBase + wc + hd];
                    *(short*)(tb + hd * 128 + ((kvl * 2) ^ ((hd & 7) << 4))) = f2bf(v);
                }
            }
        }
        asm volatile("s_waitcnt lgkmcnt(0)" ::: "memory");  // wave-local
        #pragma unroll
        for (int c = 0; c < 8; ++c) {
            const int u  = c * 64 + lane;
            const int hd = u >> 3;
            const int kc = u & 7;
            s16x8 vv = *(const s16x8*)(tb + hd * 128 + ((kc * 16) ^ ((hd & 7) << 4)));
            *(s16x8*)(outVt + ((size_t)(b * 16 + h) * 64 + hd) * 2048 + kvbase + kc * 8) = vv;
        }
    } else {
        short* Co = (z == 0) ? outQ : outK;
        #pragma unroll
        for (int m = 0; m < 4; ++m) {
            #pragma unroll
            for (int r = 0; r < 4; ++r) {
                const int grow = rowBase + wr + m * 16 + ((lane >> 4) << 2) + r;
                #pragma unroll
                for (int n = 0; n < 4; ++n) {
                    const int gcol = colBase + wc + n * 16 + (lane & 15);
                    float v = acc[m][n][r] + bias[gcol];
                    if (z == 0) {
                        v *= 0.125f;                      // fold hd^-0.5 into Q
                    } else {
                        const int bb = grow >> 11;
                        const int ss = grow & 2047;
                        const int hd = gcol & 63;
                        const int fi = hd & 31;
                        const float ang = (float)ss * __expf((float)fi * (-9.210340371976184f / 32.0f));
                        const float tr  = (hd < 32) ? sinf(ang) : cosf(ang);
                        v += tr * lemb[labels[bb] * 64 + hd];
                    }
                    Co[(size_t)grow * 1024 + gcol] = f2bf(v);
                }
            }
        }
    }
}

// ---------------------------------------------------------------------------
// Output projection: C[4096][1024] f32 = X bf16 @ W^T bf16 + bias.
__global__ __launch_bounds__(256)
void gemm_out(const short* __restrict__ X, const short* __restrict__ W,
              const float* __restrict__ bias, float* __restrict__ Cf)
{
    __shared__ __align__(16) short As[2][128 * 64];
    __shared__ __align__(16) short Bs[2][128 * 64];
    const int tid  = threadIdx.x;
    const int lane = tid & 63;
    const int wid  = tid >> 6;
    const int rowBase = blockIdx.y * 128;
    const int colBase = blockIdx.x * 128;
    const int wr = (wid >> 1) * 64;
    const int wc = (wid & 1) * 64;

    f32x4 acc[4][4] = {};

    auto stage = [&](int buf, int k0) {
        #pragma unroll
        for (int c = 0; c < 4; ++c) {
            const int u   = (wid * 4 + c) * 64 + lane;
            const int row = u >> 3;
            const int k8a = (u & 7) ^ (row & 7);
            GLDS16(X + (size_t)(rowBase + row) * 1024 + k0 + k8a * 8,
                   &As[buf][(wid * 4 + c) * 512]);
            GLDS16(W + (size_t)(colBase + row) * 1024 + k0 + k8a * 8,
                   &Bs[buf][(wid * 4 + c) * 512]);
        }
    };

    stage(0, 0);
    __syncthreads();

    for (int t = 0; t < 16; ++t) {
        const int cur = t & 1;
        if (t < 15) stage(cur ^ 1, (t + 1) * 64);
        #pragma unroll
        for (int ks = 0; ks < 2; ++ks) {
            const int kb = ks * 64 + ((lane >> 4) << 4);
            s16x8 af[4], bfv[4];
            #pragma unroll
            for (int m = 0; m < 4; ++m) {
                const int row = wr + m * 16 + (lane & 15);
                af[m] = *(const s16x8*)((const char*)&As[cur][0] + row * 128 + (kb ^ ((row & 7) << 4)));
            }
            #pragma unroll
            for (int n = 0; n < 4; ++n) {
                const int row = wc + n * 16 + (lane & 15);
                bfv[n] = *(const s16x8*)((const char*)&Bs[cur][0] + row * 128 + (kb ^ ((row & 7) << 4)));
            }
            #pragma unroll
            for (int m = 0; m < 4; ++m)
                #pragma unroll
                for (int n = 0; n < 4; ++n)
                    acc[m][n] = __builtin_amdgcn_mfma_f32_16x16x32_bf16(af[m], bfv[n], acc[m][n], 0, 0, 0);
        }
        __syncthreads();
    }

    #pragma unroll
    for (int m = 0; m < 4; ++m) {
        #pragma unroll
        for (int r = 0; r < 4; ++r) {
            const int grow = rowBase + wr + m * 16 + ((lane >> 4) << 2) + r;
            #pragma unroll
            for (int n = 0; n < 4; ++n) {
                const int gcol = colBase + wc + n * 16 + (lane & 15);
                Cf[(size_t)grow * 1024 + gcol] = acc[m][n][r] + bias[gcol];
            }
        }
    }
}

// ---------------------------------------------------------------------------
// Flash attention. grid (32 qt, 32 bh), 4 waves x 16 q-rows. KVBLK=64,
// K and V^T staged via global_load_lds, double-buffered; defer-max softmax;
// per-lane deferred l-sum (reduced once at end).
__global__ __launch_bounds__(256)
void attn_fwd(const short* __restrict__ Q, const short* __restrict__ K,
              const short* __restrict__ Vt, short* __restrict__ AO)
{
    __shared__ __align__(16) short Ks[2][64 * 64];
    __shared__ __align__(16) short Vs[2][64 * 64];
    __shared__ __align__(16) short Ps[4][16 * 64];
    const int tid  = threadIdx.x;
    const int lane = tid & 63;
    const int wid  = tid >> 6;
    const int qt = blockIdx.x;
    const int bh = blockIdx.y;
    const int b  = bh >> 4, h = bh & 15;
    const int qrow0 = b * 2048 + qt * 64;
    const int hoff  = h * 64;
    const short* Kb = K + (size_t)b * 2048 * 1024 + hoff;
    const short* Vb = Vt + (size_t)bh * 64 * 2048;

    s16x8 qf[2];   // Q pre-scaled by 0.125 in gemm_qkv
    {
        const int qr = qrow0 + wid * 16 + (lane & 15);
        const short* qp = Q + (size_t)qr * 1024 + hoff + ((lane >> 4) << 3);
        qf[0] = *(const s16x8*)(qp);
        qf[1] = *(const s16x8*)(qp + 32);
    }

    auto stage = [&](int buf, int kv0) {
        #pragma unroll
        for (int c = 0; c < 2; ++c) {
            const int ub  = c * 256 + wid * 64;   // wave-uniform chunk base
            const int u   = ub + lane;
            const int row = u >> 3;
            const int k8  = (u & 7) ^ (row & 7);
            GLDS16(Kb + (size_t)(kv0 + row) * 1024 + k8 * 8, &Ks[buf][ub * 8]);
            GLDS16(Vb + (size_t)row * 2048 + kv0 + k8 * 8,   &Vs[buf][ub * 8]);
        }
    };

    float mrun[4], lsum[4];
    f32x4 o[4] = {};
    #pragma unroll
    for (int r = 0; r < 4; ++r) { mrun[r] = -1e30f; lsum[r] = 0.f; }

    stage(0, 0);
    __syncthreads();

    for (int t = 0; t < 32; ++t) {
        const int cur = t & 1;
        if (t < 31) stage(cur ^ 1, (t + 1) * 64);

        // S = Q K^T (pre-scaled)
        f32x4 s[4] = {};
        #pragma unroll
        for (int ks = 0; ks < 2; ++ks) {
            const int kb = ks * 64 + ((lane >> 4) << 4);
            #pragma unroll
            for (int n = 0; n < 4; ++n) {
                const int row = n * 16 + (lane & 15);
                s16x8 kf = *(const s16x8*)((const char*)&Ks[cur][0] + row * 128 + (kb ^ ((row & 7) << 4)));
                s[n] = __builtin_amdgcn_mfma_f32_16x16x32_bf16(qf[ks], kf, s[n], 0, 0, 0);
            }
        }

        // defer-max online softmax
        float pm[4];
        bool need = false;
        #pragma unroll
        for (int r = 0; r < 4; ++r) {
            pm[r] = fmaxf(fmaxf(s[0][r], s[1][r]), fmaxf(s[2][r], s[3][r]));
            need = need || (pm[r] > mrun[r] + 8.0f);
        }
        if (__any(need)) {
            #pragma unroll
            for (int r = 0; r < 4; ++r) {
                float t2 = pm[r];
                t2 = fmaxf(t2, __shfl_xor(t2, 1));
                t2 = fmaxf(t2, __shfl_xor(t2, 2));
                t2 = fmaxf(t2, __shfl_xor(t2, 4));
                t2 = fmaxf(t2, __shfl_xor(t2, 8));
                const float mn = fmaxf(mrun[r], t2);
                const float al = __expf(mrun[r] - mn);
                mrun[r] = mn;
                lsum[r] *= al;
                #pragma unroll
                for (int n = 0; n < 4; ++n) o[n][r] *= al;
            }
        }
        #pragma unroll
        for (int n = 0; n < 4; ++n) {
            #pragma unroll
            for (int r = 0; r < 4; ++r) {
                const float p = __expf(s[n][r] - mrun[r]);   // bounded by e^8
                lsum[r] += p;
                const int row = ((lane >> 4) << 2) + r;
                const int col = n * 16 + (lane & 15);
                *(short*)((char*)&Ps[wid][0] + row * 128 + ((col * 2) ^ ((row & 7) << 4))) = f2bf(p);
            }
        }
        asm volatile("s_waitcnt lgkmcnt(0)" ::: "memory");   // wave-local P ready

        // O += P @ V
        #pragma unroll
        for (int ks = 0; ks < 2; ++ks) {
            const int kb = ks * 64 + ((lane >> 4) << 4);
            const int prow = lane & 15;
            s16x8 pa = *(const s16x8*)((const char*)&Ps[wid][0] + prow * 128 + (kb ^ ((prow & 7) << 4)));
            #pragma unroll
            for (int n = 0; n < 4; ++n) {
                const int row = n * 16 + (lane & 15);
                s16x8 vb = *(const s16x8*)((const char*)&Vs[cur][0] + row * 128 + (kb ^ ((row & 7) << 4)));
                o[n] = __builtin_amdgcn_mfma_f32_16x16x32_bf16(pa, vb, o[n], 0, 0, 0);
            }
        }
        __syncthreads();   // drains prefetch vmcnt; all reads of cur done
    }

    #pragma unroll
    for (int r = 0; r < 4; ++r) {
        float tt = lsum[r];
        tt += __shfl_xor(tt, 1);
        tt += __shfl_xor(tt, 2);
        tt += __shfl_xor(tt, 4);
        tt += __shfl_xor(tt, 8);
        const float inv = 1.0f / tt;
        const int grow = qrow0 + wid * 16 + ((lane >> 4) << 2) + r;
        #pragma unroll
        for (int n = 0; n < 4; ++n) {
            const int gcol = hoff + n * 16 + (lane & 15);
            AO[(size_t)grow * 1024 + gcol] = f2bf(o[n][r] * inv);
        }
    }
}

extern "C" void kernel_launch(void* const* d_in, const int* in_sizes, int n_in,
                              void* d_out, int out_size, void* d_ws, size_t ws_size,
                              hipStream_t stream) {
    const float* vis    = (const float*)d_in[0];
    const float* aud    = (const float*)d_in[1];
    const int*   labels = (const int*)d_in[2];
    const float* Wq = (const float*)d_in[3];  const float* bq = (const float*)d_in[4];
    const float* Wk = (const float*)d_in[5];  const float* bk = (const float*)d_in[6];
    const float* Wv = (const float*)d_in[7];  const float* bv = (const float*)d_in[8];
    const float* Wo = (const float*)d_in[9];  const float* bo = (const float*)d_in[10];
    const float* lemb = (const float*)d_in[11];

    short* wsQ   = (short*)d_ws;              // 4M shorts each
    short* wsK   = wsQ  + 4194304;
    short* wsVt  = wsK  + 4194304;            // [32 bh][64 d][2048 kv]
    short* wsAO  = wsVt + 4194304;
    short* visB  = wsAO + 4194304;
    short* audB  = visB + 4194304;
    short* WqB   = audB + 4194304;
    short* WkB   = WqB  + 1048576;
    short* WvB   = WkB  + 1048576;
    short* WoB   = WvB  + 1048576;
    float* out   = (float*)d_out;

    cvt_all<<<6144, 256, 0, stream>>>(vis, aud, Wq, Wk, Wv, Wo,
                                      visB, audB, WqB, WkB, WvB, WoB);
    gemm_qkv<<<dim3(8, 32, 3), 256, 0, stream>>>(visB, audB, WqB, WkB, WvB,
                                                 bq, bk, bv, wsQ, wsK, wsVt,
                                                 labels, lemb);
    attn_fwd<<<dim3(32, 32), 256, 0, stream>>>(wsQ, wsK, wsVt, wsAO);
    gemm_out<<<dim3(8, 32), 256, 0, stream>>>(wsAO, WoB, bo, out);
}

// Round 5
// 248.909 us; speedup vs baseline: 2.1425x; 1.0514x over previous
//
#include <hip/hip_runtime.h>
#include <hip/hip_bf16.h>

// AudioCrossAttention on MI355X (gfx950).
// cvt(f32->bf16) | gemm_qkv 64x128-tile (Q prescaled; K+lrope; V -> V^T) |
// flash-attn (swapped QK^T, in-lane softmax, b64 P path) | gemm_out 64x128.

typedef short s16x8 __attribute__((ext_vector_type(8)));
typedef float f32x4 __attribute__((ext_vector_type(4)));

__device__ __forceinline__ short f2bf(float f) {
    unsigned u = __float_as_uint(f);
    u = u + 0x7fffu + ((u >> 16) & 1u);   // RNE
    return (short)(u >> 16);
}

__device__ __forceinline__ unsigned cvtpk(float lo, float hi) {
    unsigned r;
    asm volatile("v_cvt_pk_bf16_f32 %0, %1, %2" : "=v"(r) : "v"(lo), "v"(hi));
    return r;
}

#define GLDS16(g, l)                                                          \
    __builtin_amdgcn_global_load_lds(                                         \
        (const __attribute__((address_space(1))) void*)(g),                   \
        (__attribute__((address_space(3))) void*)(l), 16, 0, 0)

// ---------------------------------------------------------------------------
__global__ __launch_bounds__(256)
void cvt_all(const float* __restrict__ vis, const float* __restrict__ aud,
             const float* __restrict__ Wq, const float* __restrict__ Wk,
             const float* __restrict__ Wv, const float* __restrict__ Wo,
             short* __restrict__ visB, short* __restrict__ audB,
             short* __restrict__ WqB, short* __restrict__ WkB,
             short* __restrict__ WvB, short* __restrict__ WoB)
{
    const int bid = blockIdx.x;
    const float* src; short* dst; int vec0;
    if (bid < 2048)      { src = vis; dst = visB; vec0 = bid * 256; }
    else if (bid < 4096) { src = aud; dst = audB; vec0 = (bid - 2048) * 256; }
    else {
        const int r = bid - 4096, w = r >> 9, lb = r & 511;
        vec0 = lb * 256;
        if      (w == 0) { src = Wq; dst = WqB; }
        else if (w == 1) { src = Wk; dst = WkB; }
        else if (w == 2) { src = Wv; dst = WvB; }
        else             { src = Wo; dst = WoB; }
    }
    const int i = (vec0 + threadIdx.x) * 8;
    float4 a = *(const float4*)(src + i);
    float4 b = *(const float4*)(src + i + 4);
    s16x8 o;
    o[0]=f2bf(a.x); o[1]=f2bf(a.y); o[2]=f2bf(a.z); o[3]=f2bf(a.w);
    o[4]=f2bf(b.x); o[5]=f2bf(b.y); o[6]=f2bf(b.z); o[7]=f2bf(b.w);
    *(s16x8*)(dst + i) = o;
}

// ---------------------------------------------------------------------------
// Fused Q/K/V projection, 64(M)x128(N) tile, BK=64, grid (8, 64, 3).
// z: 0=Q (prescaled 0.125), 1=K (+lrope), 2=V (writes V^T [bh][64 d][2048 kv]).
__global__ __launch_bounds__(256)
void gemm_qkv(const short* __restrict__ visB, const short* __restrict__ audB,
              const short* __restrict__ WqB, const short* __restrict__ WkB,
              const short* __restrict__ WvB,
              const float* __restrict__ bq, const float* __restrict__ bk,
              const float* __restrict__ bv,
              short* __restrict__ outQ, short* __restrict__ outK,
              short* __restrict__ outVt,
              const int* __restrict__ labels, const float* __restrict__ lemb)
{
    __shared__ __align__(16) short As[2][64 * 64];
    __shared__ __align__(16) short Bs[2][128 * 64];
    const int tid  = threadIdx.x;
    const int lane = tid & 63;
    const int wid  = tid >> 6;
    const int q15  = lane & 15;
    const int hi   = lane >> 4;
    const int z    = blockIdx.z;
    const int rowBase = blockIdx.y * 64;
    const int colBase = blockIdx.x * 128;
    const int wr = (wid >> 1) * 32;
    const int wc = (wid & 1) * 64;
    const short* X = (z == 0) ? visB : audB;
    const short* W = (z == 0) ? WqB : (z == 1) ? WkB : WvB;
    const float* bias = (z == 0) ? bq : (z == 1) ? bk : bv;

    f32x4 acc[2][4] = {};

    auto stage = [&](int buf, int k0) {
        #pragma unroll
        for (int c = 0; c < 2; ++c) {
            const int u   = c * 256 + tid;
            const int row = u >> 3;
            const int k8a = (u & 7) ^ (row & 7);
            GLDS16(X + (size_t)(rowBase + row) * 1024 + k0 + k8a * 8,
                   &As[buf][(c * 256 + wid * 64) * 8]);
        }
        #pragma unroll
        for (int c = 0; c < 4; ++c) {
            const int u   = c * 256 + tid;
            const int row = u >> 3;
            const int k8a = (u & 7) ^ (row & 7);
            GLDS16(W + (size_t)(colBase + row) * 1024 + k0 + k8a * 8,
                   &Bs[buf][(c * 256 + wid * 64) * 8]);
        }
    };

    stage(0, 0);
    __syncthreads();

    for (int t = 0; t < 16; ++t) {
        const int cur = t & 1;
        if (t < 15) stage(cur ^ 1, (t + 1) * 64);
        #pragma unroll
        for (int ks = 0; ks < 2; ++ks) {
            const int kb = ks * 64 + (hi << 4);
            s16x8 af[2], bfv[4];
            #pragma unroll
            for (int m = 0; m < 2; ++m) {
                const int row = wr + m * 16 + q15;
                af[m] = *(const s16x8*)((const char*)&As[cur][0] + row * 128 + (kb ^ ((row & 7) << 4)));
            }
            #pragma unroll
            for (int n = 0; n < 4; ++n) {
                const int row = wc + n * 16 + q15;
                bfv[n] = *(const s16x8*)((const char*)&Bs[cur][0] + row * 128 + (kb ^ ((row & 7) << 4)));
            }
            #pragma unroll
            for (int m = 0; m < 2; ++m)
                #pragma unroll
                for (int n = 0; n < 4; ++n)
                    acc[m][n] = __builtin_amdgcn_mfma_f32_16x16x32_bf16(af[m], bfv[n], acc[m][n], 0, 0, 0);
        }
        __syncthreads();
    }

    if (z == 2) {
        __syncthreads();   // all waves done with As before scratch reuse (r4 race fix)
        // Per-wave transpose scratch: 64 d x 32 kv (one head), 4 KB in As.
        char* tb = (char*)&As[0][0] + wid * 4096;
        const int b  = rowBase >> 11;
        const int h  = (colBase + wc) >> 6;
        const int kvbase = (rowBase & 2047) + wr;
        #pragma unroll
        for (int m = 0; m < 2; ++m) {
            #pragma unroll
            for (int r = 0; r < 4; ++r) {
                const int kvl = m * 16 + hi * 4 + r;
                #pragma unroll
                for (int n = 0; n < 4; ++n) {
                    const int hd = n * 16 + q15;
                    const float v = acc[m][n][r] + bias[colBase + wc + hd];
                    *(short*)(tb + hd * 64 + ((kvl * 2) ^ ((hd & 3) << 4))) = f2bf(v);
                }
            }
        }
        asm volatile("s_waitcnt lgkmcnt(0)" ::: "memory");  // wave-local
        #pragma unroll
        for (int c = 0; c < 4; ++c) {
            const int u  = c * 64 + lane;
            const int hd = u >> 2;
            const int kc = u & 3;
            s16x8 vv = *(const s16x8*)(tb + hd * 64 + ((kc * 16) ^ ((hd & 3) << 4)));
            *(s16x8*)(outVt + ((size_t)(b * 16 + h) * 64 + hd) * 2048 + kvbase + kc * 8) = vv;
        }
    } else {
        short* Co = (z == 0) ? outQ : outK;
        #pragma unroll
        for (int m = 0; m < 2; ++m) {
            #pragma unroll
            for (int r = 0; r < 4; ++r) {
                const int grow = rowBase + wr + m * 16 + hi * 4 + r;
                #pragma unroll
                for (int n = 0; n < 4; ++n) {
                    const int gcol = colBase + wc + n * 16 + q15;
                    float v = acc[m][n][r] + bias[gcol];
                    if (z == 0) {
                        v *= 0.125f;                      // fold hd^-0.5 into Q
                    } else {
                        const int bb = grow >> 11;
                        const int ss = grow & 2047;
                        const int hd = gcol & 63;
                        const int fi = hd & 31;
                        const float ang = (float)ss * __expf((float)fi * (-9.210340371976184f / 32.0f));
                        const float tr  = (hd < 32) ? sinf(ang) : cosf(ang);
                        v += tr * lemb[labels[bb] * 64 + hd];
                    }
                    Co[(size_t)grow * 1024 + gcol] = f2bf(v);
                }
            }
        }
    }
}

// ---------------------------------------------------------------------------
// Output projection, 64x128 tile, grid (8, 64): C f32 = X bf16 @ W^T + bias.
__global__ __launch_bounds__(256)
void gemm_out(const short* __restrict__ X, const short* __restrict__ W,
              const float* __restrict__ bias, float* __restrict__ Cf)
{
    __shared__ __align__(16) short As[2][64 * 64];
    __shared__ __align__(16) short Bs[2][128 * 64];
    const int tid  = threadIdx.x;
    const int lane = tid & 63;
    const int wid  = tid >> 6;
    const int q15  = lane & 15;
    const int hi   = lane >> 4;
    const int rowBase = blockIdx.y * 64;
    const int colBase = blockIdx.x * 128;
    const int wr = (wid >> 1) * 32;
    const int wc = (wid & 1) * 64;

    f32x4 acc[2][4] = {};

    auto stage = [&](int buf, int k0) {
        #pragma unroll
        for (int c = 0; c < 2; ++c) {
            const int u   = c * 256 + tid;
            const int row = u >> 3;
            const int k8a = (u & 7) ^ (row & 7);
            GLDS16(X + (size_t)(rowBase + row) * 1024 + k0 + k8a * 8,
                   &As[buf][(c * 256 + wid * 64) * 8]);
        }
        #pragma unroll
        for (int c = 0; c < 4; ++c) {
            const int u   = c * 256 + tid;
            const int row = u >> 3;
            const int k8a = (u & 7) ^ (row & 7);
            GLDS16(W + (size_t)(colBase + row) * 1024 + k0 + k8a * 8,
                   &Bs[buf][(c * 256 + wid * 64) * 8]);
        }
    };

    stage(0, 0);
    __syncthreads();

    for (int t = 0; t < 16; ++t) {
        const int cur = t & 1;
        if (t < 15) stage(cur ^ 1, (t + 1) * 64);
        #pragma unroll
        for (int ks = 0; ks < 2; ++ks) {
            const int kb = ks * 64 + (hi << 4);
            s16x8 af[2], bfv[4];
            #pragma unroll
            for (int m = 0; m < 2; ++m) {
                const int row = wr + m * 16 + q15;
                af[m] = *(const s16x8*)((const char*)&As[cur][0] + row * 128 + (kb ^ ((row & 7) << 4)));
            }
            #pragma unroll
            for (int n = 0; n < 4; ++n) {
                const int row = wc + n * 16 + q15;
                bfv[n] = *(const s16x8*)((const char*)&Bs[cur][0] + row * 128 + (kb ^ ((row & 7) << 4)));
            }
            #pragma unroll
            for (int m = 0; m < 2; ++m)
                #pragma unroll
                for (int n = 0; n < 4; ++n)
                    acc[m][n] = __builtin_amdgcn_mfma_f32_16x16x32_bf16(af[m], bfv[n], acc[m][n], 0, 0, 0);
        }
        __syncthreads();
    }

    #pragma unroll
    for (int m = 0; m < 2; ++m) {
        #pragma unroll
        for (int r = 0; r < 4; ++r) {
            const int grow = rowBase + wr + m * 16 + hi * 4 + r;
            #pragma unroll
            for (int n = 0; n < 4; ++n) {
                const int gcol = colBase + wc + n * 16 + q15;
                Cf[(size_t)grow * 1024 + gcol] = acc[m][n][r] + bias[gcol];
            }
        }
    }
}

// ---------------------------------------------------------------------------
// Flash attention, swapped QK^T. grid (32 qt, 32 bh), 4 waves x 16 q-rows.
// S^T = mfma(K, Q): lane owns q = lane&15, kv = n*16 + hi*4 + r -> per-lane
// softmax, kv-contiguous P pairs -> 4 ds_write_b64 + 2 ds_read_b128 per tile.
__global__ __launch_bounds__(256)
void attn_fwd(const short* __restrict__ Q, const short* __restrict__ K,
              const short* __restrict__ Vt, short* __restrict__ AO)
{
    __shared__ __align__(16) short Ks[2][64 * 64];
    __shared__ __align__(16) short Vs[2][64 * 64];
    __shared__ __align__(16) short Ps[4][16 * 64];   // per-wave P [q][kv], swizzled
    const int tid  = threadIdx.x;
    const int lane = tid & 63;
    const int wid  = tid >> 6;
    const int q15  = lane & 15;
    const int hi   = lane >> 4;
    const int qt = blockIdx.x;
    const int bh = blockIdx.y;
    const int b  = bh >> 4, h = bh & 15;
    const int qrow0 = b * 2048 + qt * 64;
    const int hoff  = h * 64;
    const short* Kb = K + (size_t)b * 2048 * 1024 + hoff;
    const short* Vb = Vt + (size_t)bh * 64 * 2048;
    char* pw = (char*)&Ps[wid][0];
    const int psw = (q15 & 7) << 4;                  // P swizzle mask

    s16x8 qf[2];   // Q pre-scaled by 0.125; lane&15 = q-row, hi*8 = d-chunk
    {
        const int qr = qrow0 + wid * 16 + q15;
        const short* qp = Q + (size_t)qr * 1024 + hoff + hi * 8;
        qf[0] = *(const s16x8*)(qp);
        qf[1] = *(const s16x8*)(qp + 32);
    }

    auto stage = [&](int buf, int kv0) {
        #pragma unroll
        for (int c = 0; c < 2; ++c) {
            const int ub  = c * 256 + wid * 64;
            const int u   = ub + lane;
            const int row = u >> 3;
            const int k8  = (u & 7) ^ (row & 7);
            GLDS16(Kb + (size_t)(kv0 + row) * 1024 + k8 * 8, &Ks[buf][ub * 8]);
            GLDS16(Vb + (size_t)row * 2048 + kv0 + k8 * 8,   &Vs[buf][ub * 8]);
        }
    };

    float mrun = -1e30f, lsum = 0.f;
    f32x4 o[4] = {};

    stage(0, 0);
    __syncthreads();

    for (int t = 0; t < 32; ++t) {
        const int cur = t & 1;
        if (t < 31) stage(cur ^ 1, (t + 1) * 64);

        // S^T = K @ Q^T: s[n][r] = S[q15][kv = n*16 + hi*4 + r]
        f32x4 s[4] = {};
        #pragma unroll
        for (int ks = 0; ks < 2; ++ks) {
            const int kb = ks * 64 + (hi << 4);
            #pragma unroll
            for (int n = 0; n < 4; ++n) {
                const int row = n * 16 + q15;
                s16x8 kf = *(const s16x8*)((const char*)&Ks[cur][0] + row * 128 + (kb ^ ((row & 7) << 4)));
                s[n] = __builtin_amdgcn_mfma_f32_16x16x32_bf16(kf, qf[ks], s[n], 0, 0, 0);
            }
        }

        // per-lane defer-max softmax
        float pm = s[0][0];
        #pragma unroll
        for (int n = 0; n < 4; ++n)
            #pragma unroll
            for (int r = 0; r < 4; ++r) pm = fmaxf(pm, s[n][r]);
        if (__any(pm > mrun + 8.0f)) {
            float t2 = fmaxf(pm, __shfl_xor(pm, 16));
            t2 = fmaxf(t2, __shfl_xor(t2, 32));
            const float mn = fmaxf(mrun, t2);
            const float al = __expf(mrun - mn);
            mrun = mn;
            lsum *= al;
            float alq[4];
            #pragma unroll
            for (int r = 0; r < 4; ++r) alq[r] = __shfl(al, hi * 4 + r);
            #pragma unroll
            for (int n = 0; n < 4; ++n)
                #pragma unroll
                for (int r = 0; r < 4; ++r) o[n][r] *= alq[r];
        }
        #pragma unroll
        for (int n = 0; n < 4; ++n) {
            float p0 = __expf(s[n][0] - mrun);
            float p1 = __expf(s[n][1] - mrun);
            float p2 = __expf(s[n][2] - mrun);
            float p3 = __expf(s[n][3] - mrun);
            lsum += (p0 + p1) + (p2 + p3);
            uint2 pk;
            pk.x = cvtpk(p0, p1);
            pk.y = cvtpk(p2, p3);
            *(uint2*)(pw + q15 * 128 + ((n * 32 + hi * 8) ^ psw)) = pk;
        }
        asm volatile("s_waitcnt lgkmcnt(0)" ::: "memory");   // wave-local P ready

        // O += P @ V : A = P[q15][kv-chunk], B = V^T[d][kv-chunk]
        #pragma unroll
        for (int ks = 0; ks < 2; ++ks) {
            const int kb = ks * 64 + (hi << 4);
            s16x8 pa = *(const s16x8*)(pw + q15 * 128 + ((ks * 64 + hi * 16) ^ psw));
            #pragma unroll
            for (int n = 0; n < 4; ++n) {
                const int row = n * 16 + q15;
                s16x8 vb = *(const s16x8*)((const char*)&Vs[cur][0] + row * 128 + (kb ^ ((row & 7) << 4)));
                o[n] = __builtin_amdgcn_mfma_f32_16x16x32_bf16(pa, vb, o[n], 0, 0, 0);
            }
        }
        __syncthreads();   // drains prefetch vmcnt; all reads of cur done
    }

    // final normalize: lsum reduce across hi-lanes, then lane-transpose to O side
    float tt = lsum;
    tt += __shfl_xor(tt, 16);
    tt += __shfl_xor(tt, 32);
    const float inv = 1.0f / tt;
    float invq[4];
    #pragma unroll
    for (int r = 0; r < 4; ++r) invq[r] = __shfl(inv, hi * 4 + r);
    #pragma unroll
    for (int r = 0; r < 4; ++r) {
        const int grow = qrow0 + wid * 16 + hi * 4 + r;
        #pragma unroll
        for (int n = 0; n < 4; ++n) {
            const int gcol = hoff + n * 16 + q15;
            AO[(size_t)grow * 1024 + gcol] = f2bf(o[n][r] * invq[r]);
        }
    }
}

extern "C" void kernel_launch(void* const* d_in, const int* in_sizes, int n_in,
                              void* d_out, int out_size, void* d_ws, size_t ws_size,
                              hipStream_t stream) {
    const float* vis    = (const float*)d_in[0];
    const float* aud    = (const float*)d_in[1];
    const int*   labels = (const int*)d_in[2];
    const float* Wq = (const float*)d_in[3];  const float* bq = (const float*)d_in[4];
    const float* Wk = (const float*)d_in[5];  const float* bk = (const float*)d_in[6];
    const float* Wv = (const float*)d_in[7];  const float* bv = (const float*)d_in[8];
    const float* Wo = (const float*)d_in[9];  const float* bo = (const float*)d_in[10];
    const float* lemb = (const float*)d_in[11];

    short* wsQ   = (short*)d_ws;              // 4M shorts each
    short* wsK   = wsQ  + 4194304;
    short* wsVt  = wsK  + 4194304;            // [32 bh][64 d][2048 kv]
    short* wsAO  = wsVt + 4194304;
    short* visB  = wsAO + 4194304;
    short* audB  = visB + 4194304;
    short* WqB   = audB + 4194304;
    short* WkB   = WqB  + 1048576;
    short* WvB   = WkB  + 1048576;
    short* WoB   = WvB  + 1048576;
    float* out   = (float*)d_out;

    cvt_all<<<6144, 256, 0, stream>>>(vis, aud, Wq, Wk, Wv, Wo,
                                      visB, audB, WqB, WkB, WvB, WoB);
    gemm_qkv<<<dim3(8, 64, 3), 256, 0, stream>>>(visB, audB, WqB, WkB, WvB,
                                                 bq, bk, bv, wsQ, wsK, wsVt,
                                                 labels, lemb);
    attn_fwd<<<dim3(32, 32), 256, 0, stream>>>(wsQ, wsK, wsVt, wsAO);
    gemm_out<<<dim3(8, 64), 256, 0, stream>>>(wsAO, WoB, bo, out);
}

// Round 6
// 244.430 us; speedup vs baseline: 2.1818x; 1.0183x over previous
//
#include <hip/hip_runtime.h>
#include <hip/hip_bf16.h>

// AudioCrossAttention on MI355X (gfx950).
// cvt(f32->bf16) | gemm_qkv 64x128-tile (Q prescaled; K+lrope; V -> V^T) |
// flash-attn (swapped QK^T, 32 q-rows/wave, shared K/V frags) | gemm_out 64x128.

typedef short s16x8 __attribute__((ext_vector_type(8)));
typedef float f32x4 __attribute__((ext_vector_type(4)));

__device__ __forceinline__ short f2bf(float f) {
    unsigned u = __float_as_uint(f);
    u = u + 0x7fffu + ((u >> 16) & 1u);   // RNE
    return (short)(u >> 16);
}

__device__ __forceinline__ unsigned cvtpk(float lo, float hi) {
    unsigned r;
    asm volatile("v_cvt_pk_bf16_f32 %0, %1, %2" : "=v"(r) : "v"(lo), "v"(hi));
    return r;
}

#define GLDS16(g, l)                                                          \
    __builtin_amdgcn_global_load_lds(                                         \
        (const __attribute__((address_space(1))) void*)(g),                   \
        (__attribute__((address_space(3))) void*)(l), 16, 0, 0)

// ---------------------------------------------------------------------------
__global__ __launch_bounds__(256)
void cvt_all(const float* __restrict__ vis, const float* __restrict__ aud,
             const float* __restrict__ Wq, const float* __restrict__ Wk,
             const float* __restrict__ Wv, const float* __restrict__ Wo,
             short* __restrict__ visB, short* __restrict__ audB,
             short* __restrict__ WqB, short* __restrict__ WkB,
             short* __restrict__ WvB, short* __restrict__ WoB)
{
    const int bid = blockIdx.x;
    const float* src; short* dst; int vec0;
    if (bid < 2048)      { src = vis; dst = visB; vec0 = bid * 256; }
    else if (bid < 4096) { src = aud; dst = audB; vec0 = (bid - 2048) * 256; }
    else {
        const int r = bid - 4096, w = r >> 9, lb = r & 511;
        vec0 = lb * 256;
        if      (w == 0) { src = Wq; dst = WqB; }
        else if (w == 1) { src = Wk; dst = WkB; }
        else if (w == 2) { src = Wv; dst = WvB; }
        else             { src = Wo; dst = WoB; }
    }
    const int i = (vec0 + threadIdx.x) * 8;
    float4 a = *(const float4*)(src + i);
    float4 b = *(const float4*)(src + i + 4);
    s16x8 o;
    o[0]=f2bf(a.x); o[1]=f2bf(a.y); o[2]=f2bf(a.z); o[3]=f2bf(a.w);
    o[4]=f2bf(b.x); o[5]=f2bf(b.y); o[6]=f2bf(b.z); o[7]=f2bf(b.w);
    *(s16x8*)(dst + i) = o;
}

// ---------------------------------------------------------------------------
// Fused Q/K/V projection, 64(M)x128(N) tile, BK=64, grid (8, 64, 3).
// z: 0=Q (prescaled 0.125), 1=K (+lrope), 2=V (writes V^T [bh][64 d][2048 kv]).
__global__ __launch_bounds__(256)
void gemm_qkv(const short* __restrict__ visB, const short* __restrict__ audB,
              const short* __restrict__ WqB, const short* __restrict__ WkB,
              const short* __restrict__ WvB,
              const float* __restrict__ bq, const float* __restrict__ bk,
              const float* __restrict__ bv,
              short* __restrict__ outQ, short* __restrict__ outK,
              short* __restrict__ outVt,
              const int* __restrict__ labels, const float* __restrict__ lemb)
{
    __shared__ __align__(16) short As[2][64 * 64];
    __shared__ __align__(16) short Bs[2][128 * 64];
    const int tid  = threadIdx.x;
    const int lane = tid & 63;
    const int wid  = tid >> 6;
    const int q15  = lane & 15;
    const int hi   = lane >> 4;
    const int z    = blockIdx.z;
    const int rowBase = blockIdx.y * 64;
    const int colBase = blockIdx.x * 128;
    const int wr = (wid >> 1) * 32;
    const int wc = (wid & 1) * 64;
    const short* X = (z == 0) ? visB : audB;
    const short* W = (z == 0) ? WqB : (z == 1) ? WkB : WvB;
    const float* bias = (z == 0) ? bq : (z == 1) ? bk : bv;

    f32x4 acc[2][4] = {};

    auto stage = [&](int buf, int k0) {
        #pragma unroll
        for (int c = 0; c < 2; ++c) {
            const int u   = c * 256 + tid;
            const int row = u >> 3;
            const int k8a = (u & 7) ^ (row & 7);
            GLDS16(X + (size_t)(rowBase + row) * 1024 + k0 + k8a * 8,
                   &As[buf][(c * 256 + wid * 64) * 8]);
        }
        #pragma unroll
        for (int c = 0; c < 4; ++c) {
            const int u   = c * 256 + tid;
            const int row = u >> 3;
            const int k8a = (u & 7) ^ (row & 7);
            GLDS16(W + (size_t)(colBase + row) * 1024 + k0 + k8a * 8,
                   &Bs[buf][(c * 256 + wid * 64) * 8]);
        }
    };

    stage(0, 0);
    __syncthreads();

    for (int t = 0; t < 16; ++t) {
        const int cur = t & 1;
        if (t < 15) stage(cur ^ 1, (t + 1) * 64);
        #pragma unroll
        for (int ks = 0; ks < 2; ++ks) {
            const int kb = ks * 64 + (hi << 4);
            s16x8 af[2], bfv[4];
            #pragma unroll
            for (int m = 0; m < 2; ++m) {
                const int row = wr + m * 16 + q15;
                af[m] = *(const s16x8*)((const char*)&As[cur][0] + row * 128 + (kb ^ ((row & 7) << 4)));
            }
            #pragma unroll
            for (int n = 0; n < 4; ++n) {
                const int row = wc + n * 16 + q15;
                bfv[n] = *(const s16x8*)((const char*)&Bs[cur][0] + row * 128 + (kb ^ ((row & 7) << 4)));
            }
            #pragma unroll
            for (int m = 0; m < 2; ++m)
                #pragma unroll
                for (int n = 0; n < 4; ++n)
                    acc[m][n] = __builtin_amdgcn_mfma_f32_16x16x32_bf16(af[m], bfv[n], acc[m][n], 0, 0, 0);
        }
        __syncthreads();
    }

    if (z == 2) {
        __syncthreads();   // all waves done with As before scratch reuse
        // Per-wave transpose scratch: 64 d x 32 kv (one head), 4 KB in As.
        char* tb = (char*)&As[0][0] + wid * 4096;
        const int b  = rowBase >> 11;
        const int h  = (colBase + wc) >> 6;
        const int kvbase = (rowBase & 2047) + wr;
        #pragma unroll
        for (int m = 0; m < 2; ++m) {
            #pragma unroll
            for (int r = 0; r < 4; ++r) {
                const int kvl = m * 16 + hi * 4 + r;
                #pragma unroll
                for (int n = 0; n < 4; ++n) {
                    const int hd = n * 16 + q15;
                    const float v = acc[m][n][r] + bias[colBase + wc + hd];
                    *(short*)(tb + hd * 64 + ((kvl * 2) ^ ((hd & 3) << 4))) = f2bf(v);
                }
            }
        }
        asm volatile("s_waitcnt lgkmcnt(0)" ::: "memory");  // wave-local
        #pragma unroll
        for (int c = 0; c < 4; ++c) {
            const int u  = c * 64 + lane;
            const int hd = u >> 2;
            const int kc = u & 3;
            s16x8 vv = *(const s16x8*)(tb + hd * 64 + ((kc * 16) ^ ((hd & 3) << 4)));
            *(s16x8*)(outVt + ((size_t)(b * 16 + h) * 64 + hd) * 2048 + kvbase + kc * 8) = vv;
        }
    } else {
        short* Co = (z == 0) ? outQ : outK;
        #pragma unroll
        for (int m = 0; m < 2; ++m) {
            #pragma unroll
            for (int r = 0; r < 4; ++r) {
                const int grow = rowBase + wr + m * 16 + hi * 4 + r;
                #pragma unroll
                for (int n = 0; n < 4; ++n) {
                    const int gcol = colBase + wc + n * 16 + q15;
                    float v = acc[m][n][r] + bias[gcol];
                    if (z == 0) {
                        v *= 0.125f;                      // fold hd^-0.5 into Q
                    } else {
                        const int bb = grow >> 11;
                        const int ss = grow & 2047;
                        const int hd = gcol & 63;
                        const int fi = hd & 31;
                        const float ang = (float)ss * __expf((float)fi * (-9.210340371976184f / 32.0f));
                        const float tr  = (hd < 32) ? sinf(ang) : cosf(ang);
                        v += tr * lemb[labels[bb] * 64 + hd];
                    }
                    Co[(size_t)grow * 1024 + gcol] = f2bf(v);
                }
            }
        }
    }
}

// ---------------------------------------------------------------------------
// Output projection, 64x128 tile, grid (8, 64): C f32 = X bf16 @ W^T + bias.
__global__ __launch_bounds__(256)
void gemm_out(const short* __restrict__ X, const short* __restrict__ W,
              const float* __restrict__ bias, float* __restrict__ Cf)
{
    __shared__ __align__(16) short As[2][64 * 64];
    __shared__ __align__(16) short Bs[2][128 * 64];
    const int tid  = threadIdx.x;
    const int lane = tid & 63;
    const int wid  = tid >> 6;
    const int q15  = lane & 15;
    const int hi   = lane >> 4;
    const int rowBase = blockIdx.y * 64;
    const int colBase = blockIdx.x * 128;
    const int wr = (wid >> 1) * 32;
    const int wc = (wid & 1) * 64;

    f32x4 acc[2][4] = {};

    auto stage = [&](int buf, int k0) {
        #pragma unroll
        for (int c = 0; c < 2; ++c) {
            const int u   = c * 256 + tid;
            const int row = u >> 3;
            const int k8a = (u & 7) ^ (row & 7);
            GLDS16(X + (size_t)(rowBase + row) * 1024 + k0 + k8a * 8,
                   &As[buf][(c * 256 + wid * 64) * 8]);
        }
        #pragma unroll
        for (int c = 0; c < 4; ++c) {
            const int u   = c * 256 + tid;
            const int row = u >> 3;
            const int k8a = (u & 7) ^ (row & 7);
            GLDS16(W + (size_t)(colBase + row) * 1024 + k0 + k8a * 8,
                   &Bs[buf][(c * 256 + wid * 64) * 8]);
        }
    };

    stage(0, 0);
    __syncthreads();

    for (int t = 0; t < 16; ++t) {
        const int cur = t & 1;
        if (t < 15) stage(cur ^ 1, (t + 1) * 64);
        #pragma unroll
        for (int ks = 0; ks < 2; ++ks) {
            const int kb = ks * 64 + (hi << 4);
            s16x8 af[2], bfv[4];
            #pragma unroll
            for (int m = 0; m < 2; ++m) {
                const int row = wr + m * 16 + q15;
                af[m] = *(const s16x8*)((const char*)&As[cur][0] + row * 128 + (kb ^ ((row & 7) << 4)));
            }
            #pragma unroll
            for (int n = 0; n < 4; ++n) {
                const int row = wc + n * 16 + q15;
                bfv[n] = *(const s16x8*)((const char*)&Bs[cur][0] + row * 128 + (kb ^ ((row & 7) << 4)));
            }
            #pragma unroll
            for (int m = 0; m < 2; ++m)
                #pragma unroll
                for (int n = 0; n < 4; ++n)
                    acc[m][n] = __builtin_amdgcn_mfma_f32_16x16x32_bf16(af[m], bfv[n], acc[m][n], 0, 0, 0);
        }
        __syncthreads();
    }

    #pragma unroll
    for (int m = 0; m < 2; ++m) {
        #pragma unroll
        for (int r = 0; r < 4; ++r) {
            const int grow = rowBase + wr + m * 16 + hi * 4 + r;
            #pragma unroll
            for (int n = 0; n < 4; ++n) {
                const int gcol = colBase + wc + n * 16 + q15;
                Cf[(size_t)grow * 1024 + gcol] = acc[m][n][r] + bias[gcol];
            }
        }
    }
}

// ---------------------------------------------------------------------------
// Flash attention, swapped QK^T, 32 q-rows per wave (2 fragments sharing the
// K/V LDS fragments). grid (16 qt, 32 bh), 4 waves -> 128 q-rows per block.
// Lane owns q = lane&15 (per fragment); kv = n*16 + hi*4 + r.
__global__ __launch_bounds__(256)
void attn_fwd(const short* __restrict__ Q, const short* __restrict__ K,
              const short* __restrict__ Vt, short* __restrict__ AO)
{
    __shared__ __align__(16) short Ks[2][64 * 64];
    __shared__ __align__(16) short Vs[2][64 * 64];
    __shared__ __align__(16) short Ps[4][32 * 64];   // per-wave P [32 q][64 kv]
    const int tid  = threadIdx.x;
    const int lane = tid & 63;
    const int wid  = tid >> 6;
    const int q15  = lane & 15;
    const int hi   = lane >> 4;
    const int qt = blockIdx.x;
    const int bh = blockIdx.y;
    const int b  = bh >> 4, h = bh & 15;
    const int qrow0 = b * 2048 + qt * 128 + wid * 32;   // wave's 32 q-rows
    const int hoff  = h * 64;
    const short* Kb = K + (size_t)b * 2048 * 1024 + hoff;
    const short* Vb = Vt + (size_t)bh * 64 * 2048;
    char* pw = (char*)&Ps[wid][0];
    const int psw = (q15 & 7) << 4;                  // P swizzle mask

    s16x8 qf[2][2];   // [fragment][ks]; Q pre-scaled by 0.125
    #pragma unroll
    for (int f = 0; f < 2; ++f) {
        const int qr = qrow0 + f * 16 + q15;
        const short* qp = Q + (size_t)qr * 1024 + hoff + hi * 8;
        qf[f][0] = *(const s16x8*)(qp);
        qf[f][1] = *(const s16x8*)(qp + 32);
    }

    auto stage = [&](int buf, int kv0) {
        #pragma unroll
        for (int c = 0; c < 2; ++c) {
            const int ub  = c * 256 + wid * 64;
            const int u   = ub + lane;
            const int row = u >> 3;
            const int k8  = (u & 7) ^ (row & 7);
            GLDS16(Kb + (size_t)(kv0 + row) * 1024 + k8 * 8, &Ks[buf][ub * 8]);
            GLDS16(Vb + (size_t)row * 2048 + kv0 + k8 * 8,   &Vs[buf][ub * 8]);
        }
    };

    float mrun[2] = {-1e30f, -1e30f}, lsum[2] = {0.f, 0.f};
    f32x4 o[2][4] = {};

    stage(0, 0);
    __syncthreads();

    for (int t = 0; t < 32; ++t) {
        const int cur = t & 1;
        if (t < 31) stage(cur ^ 1, (t + 1) * 64);

        // S^T = K @ Q^T for both fragments; kf read ONCE, used twice.
        f32x4 s[2][4] = {};
        #pragma unroll
        for (int ks = 0; ks < 2; ++ks) {
            const int kb = ks * 64 + (hi << 4);
            #pragma unroll
            for (int n = 0; n < 4; ++n) {
                const int row = n * 16 + q15;
                s16x8 kf = *(const s16x8*)((const char*)&Ks[cur][0] + row * 128 + (kb ^ ((row & 7) << 4)));
                s[0][n] = __builtin_amdgcn_mfma_f32_16x16x32_bf16(kf, qf[0][ks], s[0][n], 0, 0, 0);
                s[1][n] = __builtin_amdgcn_mfma_f32_16x16x32_bf16(kf, qf[1][ks], s[1][n], 0, 0, 0);
            }
        }

        // per-lane defer-max softmax (per fragment)
        float pm[2];
        #pragma unroll
        for (int f = 0; f < 2; ++f) {
            pm[f] = s[f][0][0];
            #pragma unroll
            for (int n = 0; n < 4; ++n)
                #pragma unroll
                for (int r = 0; r < 4; ++r) pm[f] = fmaxf(pm[f], s[f][n][r]);
        }
        if (__any((pm[0] > mrun[0] + 8.0f) || (pm[1] > mrun[1] + 8.0f))) {
            #pragma unroll
            for (int f = 0; f < 2; ++f) {
                float t2 = fmaxf(pm[f], __shfl_xor(pm[f], 16));
                t2 = fmaxf(t2, __shfl_xor(t2, 32));
                const float mn = fmaxf(mrun[f], t2);
                const float al = __expf(mrun[f] - mn);
                mrun[f] = mn;
                lsum[f] *= al;
                float alq[4];
                #pragma unroll
                for (int r = 0; r < 4; ++r) alq[r] = __shfl(al, hi * 4 + r);
                #pragma unroll
                for (int n = 0; n < 4; ++n)
                    #pragma unroll
                    for (int r = 0; r < 4; ++r) o[f][n][r] *= alq[r];
            }
        }
        #pragma unroll
        for (int f = 0; f < 2; ++f) {
            #pragma unroll
            for (int n = 0; n < 4; ++n) {
                float p0 = __expf(s[f][n][0] - mrun[f]);
                float p1 = __expf(s[f][n][1] - mrun[f]);
                float p2 = __expf(s[f][n][2] - mrun[f]);
                float p3 = __expf(s[f][n][3] - mrun[f]);
                lsum[f] += (p0 + p1) + (p2 + p3);
                uint2 pk;
                pk.x = cvtpk(p0, p1);
                pk.y = cvtpk(p2, p3);
                *(uint2*)(pw + (f * 16 + q15) * 128 + ((n * 32 + hi * 8) ^ psw)) = pk;
            }
        }
        asm volatile("s_waitcnt lgkmcnt(0)" ::: "memory");   // wave-local P ready

        // O += P @ V : vb read ONCE per (ks,n), used by both fragments.
        #pragma unroll
        for (int ks = 0; ks < 2; ++ks) {
            const int kb = ks * 64 + (hi << 4);
            s16x8 pa0 = *(const s16x8*)(pw + (q15) * 128 + ((ks * 64 + hi * 16) ^ psw));
            s16x8 pa1 = *(const s16x8*)(pw + (16 + q15) * 128 + ((ks * 64 + hi * 16) ^ psw));
            #pragma unroll
            for (int n = 0; n < 4; ++n) {
                const int row = n * 16 + q15;
                s16x8 vb = *(const s16x8*)((const char*)&Vs[cur][0] + row * 128 + (kb ^ ((row & 7) << 4)));
                o[0][n] = __builtin_amdgcn_mfma_f32_16x16x32_bf16(pa0, vb, o[0][n], 0, 0, 0);
                o[1][n] = __builtin_amdgcn_mfma_f32_16x16x32_bf16(pa1, vb, o[1][n], 0, 0, 0);
            }
        }
        __syncthreads();   // drains prefetch vmcnt; all reads of cur done
    }

    // final normalize per fragment
    #pragma unroll
    for (int f = 0; f < 2; ++f) {
        float tt = lsum[f];
        tt += __shfl_xor(tt, 16);
        tt += __shfl_xor(tt, 32);
        const float inv = 1.0f / tt;
        float invq[4];
        #pragma unroll
        for (int r = 0; r < 4; ++r) invq[r] = __shfl(inv, hi * 4 + r);
        #pragma unroll
        for (int r = 0; r < 4; ++r) {
            const int grow = qrow0 + f * 16 + hi * 4 + r;
            #pragma unroll
            for (int n = 0; n < 4; ++n) {
                const int gcol = hoff + n * 16 + q15;
                AO[(size_t)grow * 1024 + gcol] = f2bf(o[f][n][r] * invq[r]);
            }
        }
    }
}

extern "C" void kernel_launch(void* const* d_in, const int* in_sizes, int n_in,
                              void* d_out, int out_size, void* d_ws, size_t ws_size,
                              hipStream_t stream) {
    const float* vis    = (const float*)d_in[0];
    const float* aud    = (const float*)d_in[1];
    const int*   labels = (const int*)d_in[2];
    const float* Wq = (const float*)d_in[3];  const float* bq = (const float*)d_in[4];
    const float* Wk = (const float*)d_in[5];  const float* bk = (const float*)d_in[6];
    const float* Wv = (const float*)d_in[7];  const float* bv = (const float*)d_in[8];
    const float* Wo = (const float*)d_in[9];  const float* bo = (const float*)d_in[10];
    const float* lemb = (const float*)d_in[11];

    short* wsQ   = (short*)d_ws;              // 4M shorts each
    short* wsK   = wsQ  + 4194304;
    short* wsVt  = wsK  + 4194304;            // [32 bh][64 d][2048 kv]
    short* wsAO  = wsVt + 4194304;
    short* visB  = wsAO + 4194304;
    short* audB  = visB + 4194304;
    short* WqB   = audB + 4194304;
    short* WkB   = WqB  + 1048576;
    short* WvB   = WkB  + 1048576;
    short* WoB   = WvB  + 1048576;
    float* out   = (float*)d_out;

    cvt_all<<<6144, 256, 0, stream>>>(vis, aud, Wq, Wk, Wv, Wo,
                                      visB, audB, WqB, WkB, WvB, WoB);
    gemm_qkv<<<dim3(8, 64, 3), 256, 0, stream>>>(visB, audB, WqB, WkB, WvB,
                                                 bq, bk, bv, wsQ, wsK, wsVt,
                                                 labels, lemb);
    attn_fwd<<<dim3(16, 32), 256, 0, stream>>>(wsQ, wsK, wsVt, wsAO);
    gemm_out<<<dim3(8, 64), 256, 0, stream>>>(wsAO, WoB, bo, out);
}